// Round 12
// baseline (118.816 us; speedup 1.0000x reference)
//
#include <hip/hip_runtime.h>

#define NQ 10
#define QD 6
#define DIN 512
#define DOUT 64

#if defined(__has_builtin)
#if __has_builtin(__builtin_amdgcn_permlane32_swap) && __has_builtin(__builtin_amdgcn_permlane16_swap)
#define HAVE_PLSWAP 1
#endif
#endif

typedef unsigned int uv2 __attribute__((ext_vector_type(2)));

// All cross-lane via compiler intrinsics ONLY (R9/R10 lesson: inline-asm DPP
// is invisible to the hazard recognizer -> RA copies corrupt it).
template <int CTRL>
__device__ __forceinline__ float dppf(float v) {
    return __int_as_float(__builtin_amdgcn_mov_dpp(__float_as_int(v), CTRL, 0xF, 0xF, true));
}
template <int M>
__device__ __forceinline__ float sx(float v) {
    if constexpr (M == 1)       return dppf<0xB1>(v);   // quad_perm [1,0,3,2]
    else if constexpr (M == 2)  return dppf<0x4E>(v);   // quad_perm [2,3,0,1]
    else if constexpr (M == 4)  return dppf<0x1B>(dppf<0x141>(v));
    else                        return dppf<0x128>(v);  // row_ror:8
}
__device__ __forceinline__ float swz16(float v) {
    return __int_as_float(__builtin_amdgcn_ds_swizzle(__float_as_int(v), 0x401F));
}
__device__ __forceinline__ float sx32(float v, int xaddr) {
    return __int_as_float(__builtin_amdgcn_ds_bpermute(xaddr, __float_as_int(v)));
}

#if HAVE_PLSWAP
// permlane swaps with both operands = copies of v:
//   p32: vdst'=(v.lo32, v.lo32), vsrc'=(v.hi32, v.hi32)
//   p16: vdst'=(r0,r0,r2,r2),    vsrc'=(r1,r1,r3,r3)   (16-lane rows)
__device__ __forceinline__ void pl32(float v, float& pd, float& ps) {
    uv2 r = __builtin_amdgcn_permlane32_swap(__float_as_uint(v), __float_as_uint(v), false, false);
    pd = __uint_as_float(r[0]); ps = __uint_as_float(r[1]);
}
__device__ __forceinline__ void pl16(float v, float& pd, float& ps) {
    uv2 r = __builtin_amdgcn_permlane16_swap(__float_as_uint(v), __float_as_uint(v), false, false);
    pd = __uint_as_float(r[0]); ps = __uint_as_float(r[1]);
}
__device__ __forceinline__ float red64(float v, int) {
    v += dppf<0x128>(v); v += dppf<0x124>(v);
    v += dppf<0x122>(v); v += dppf<0x121>(v);
    float pd, ps;
    pl16(v, pd, ps); v = pd + ps;   // row sums -> half sums
    pl32(v, pd, ps); v = pd + ps;   // half sums -> total (all lanes)
    return v;
}
#else
__device__ __forceinline__ float red64(float v, int xaddr) {
    v += dppf<0x128>(v); v += dppf<0x124>(v);
    v += dppf<0x122>(v); v += dppf<0x121>(v);
    v += swz16(v);
    v += sx32(v, xaddr);
    return v;
}
#endif

__device__ __forceinline__ float tanh_fast(float x) {
    const float e = __expf(2.0f * x);
    return 1.0f - __fdividef(2.0f, e + 1.0f);
}

// One wave64 = one sample. Amp idx = (lane<<4) | r; wires 0..5 = lane bits
// 5..0; w6..w9 = r bits 3..0.
// CNOT fusion (validated R3..R8,R11):
//   pre-CNOT+RY : (al,be) = cbit ? ( g, C) : (C, g),  g = tbit ? S : -S
//   RY+post-CNOT: (al,be) = cbit ? (-g, C) : (C, g)
// Even phase: w0, w2+preC12, w4+preC34, w6+preC56, w8+preC78
// Odd  phase: w1+postC01, w3+postC23, w5+postC45, w7+postC67, w9+postC89
// E_0 folded into the initial state (bit relabel).
__global__ __launch_bounds__(256) void dqc_main(
    const float* __restrict__ x,
    const float* __restrict__ W1,
    const float* __restrict__ b1,
    const float* __restrict__ qw,
    const float* __restrict__ W2,
    const float* __restrict__ b2,
    float* __restrict__ out,
    const int B)
{
    // per layer (stride 24 floats):
    // [C0,S0,C2,S2,C4,S4,C6,S6,C8,S8,pad2, C1,S1,C3,S3,C5,S5,C7,S7,C9,S9,pad2]
    __shared__ __align__(16) float csl[QD * 24];

    const int tid = threadIdx.x;
    if (tid < QD * NQ) {
        const int layer = tid / NQ, wire = tid - layer * NQ;
        const float h = qw[tid] * 0.5f;
        const int pos = layer * 24 + (wire & 1) * 12 + (wire >> 1) * 2;
        csl[pos] = __cosf(h); csl[pos + 1] = __sinf(h);
    }

    const int lane = tid & 63;
    const int b = blockIdx.x * 4 + (tid >> 6);
    const int bb = (b < B) ? b : (B - 1);
    const int xaddr = ((tid ^ 32) & 63) << 2;   // bpermute addr (fallback only)

    // ---------- front-end: dot = x[b,:] @ W1 ----------
    float xr[8];
    {
        const float4* xp = (const float4*)(x + (size_t)bb * DIN + lane * 8);
        const float4 v0 = xp[0], v1 = xp[1];
        xr[0]=v0.x; xr[1]=v0.y; xr[2]=v0.z; xr[3]=v0.w;
        xr[4]=v1.x; xr[5]=v1.y; xr[6]=v1.z; xr[7]=v1.w;
    }
    float dot[NQ];
    #pragma unroll
    for (int w = 0; w < NQ; ++w) dot[w] = 0.f;
    {
        const float4* wp = (const float4*)(W1 + (size_t)lane * 8 * NQ);
        #pragma unroll
        for (int j = 0; j < 4; ++j) {
            const float4 f0 = wp[5*j], f1 = wp[5*j+1], f2 = wp[5*j+2],
                         f3 = wp[5*j+3], f4 = wp[5*j+4];
            const float xa = xr[2*j], xb = xr[2*j+1];
            dot[0]=fmaf(xa,f0.x,dot[0]); dot[1]=fmaf(xa,f0.y,dot[1]);
            dot[2]=fmaf(xa,f0.z,dot[2]); dot[3]=fmaf(xa,f0.w,dot[3]);
            dot[4]=fmaf(xa,f1.x,dot[4]); dot[5]=fmaf(xa,f1.y,dot[5]);
            dot[6]=fmaf(xa,f1.z,dot[6]); dot[7]=fmaf(xa,f1.w,dot[7]);
            dot[8]=fmaf(xa,f2.x,dot[8]); dot[9]=fmaf(xa,f2.y,dot[9]);
            dot[0]=fmaf(xb,f2.z,dot[0]); dot[1]=fmaf(xb,f2.w,dot[1]);
            dot[2]=fmaf(xb,f3.x,dot[2]); dot[3]=fmaf(xb,f3.y,dot[3]);
            dot[4]=fmaf(xb,f3.z,dot[4]); dot[5]=fmaf(xb,f3.w,dot[5]);
            dot[6]=fmaf(xb,f4.x,dot[6]); dot[7]=fmaf(xb,f4.y,dot[7]);
            dot[8]=fmaf(xb,f4.z,dot[8]); dot[9]=fmaf(xb,f4.w,dot[9]);
        }
    }
    #pragma unroll
    for (int w = 0; w < NQ; ++w) dot[w] = red64(dot[w], xaddr);

    // u0 = cos(th2+pi/4), u1 = sin(th2+pi/4), th2 = tanh(dot+b1)*pi/4
    float u0[NQ], u1[NQ];
    #pragma unroll
    for (int w = 0; w < NQ; ++w) {
        const float phi = fmaf(tanh_fast(dot[w] + b1[w]),
                               0.78539816339744830962f, 0.78539816339744830962f);
        u0[w] = __cosf(phi);
        u1[w] = __sinf(phi);
    }

    // ---------- initial product state with E_0 folded (bit relabel) ----------
    // w0@b5, w1@b4^b5, w2@b3, w3@b2^b3, w4@b1, w5@b0^b1 (lane);
    // w6@r3, w7@r2^r3, w8@r1, w9@r0^r1 (register)
    float A[16];
    {
        float lf = ((lane & 32) ? u1[0] : u0[0]);
        lf *= ((((lane >> 4) ^ (lane >> 5)) & 1) ? u1[1] : u0[1]);
        lf *= ((lane & 8) ? u1[2] : u0[2]);
        lf *= ((((lane >> 2) ^ (lane >> 3)) & 1) ? u1[3] : u0[3]);
        lf *= ((lane & 2) ? u1[4] : u0[4]);
        lf *= (((lane ^ (lane >> 1)) & 1) ? u1[5] : u0[5]);
        #pragma unroll
        for (int r = 0; r < 16; ++r) {
            float f = ((r & 8) ? u1[6] : u0[6]);
            f *= ((((r >> 2) ^ (r >> 3)) & 1) ? u1[7] : u0[7]);
            f *= ((r & 2) ? u1[8] : u0[8]);
            f *= ((((r >> 1) ^ r) & 1) ? u1[9] : u0[9]);
            A[r] = f * lf;
        }
    }

    __syncthreads();  // csl ready (no early return above)

    // ---------- 6 fused layers ----------
    #pragma unroll 1
    for (int k = 0; k < QD; ++k) {
        const float* ce = csl + k * 24;
        const bool fuse = (k != QD - 1);

        const float4 ea = *(const float4*)(ce);
        const float4 eb = *(const float4*)(ce + 4);
        const float2 ec = *(const float2*)(ce + 8);
        const float C0=ea.x,S0=ea.y, C2=ea.z,S2=ea.w;
        const float C4=eb.x,S4=eb.y, C6=eb.z,S6=eb.w;
        const float C8=ec.x,S8=ec.y;

        {   // w0 plain: partner lane^32
            const float g = (lane & 32) ? S0 : -S0;
#if HAVE_PLSWAP
            const float gd = (lane & 32) ? g : 0.f;   // vdst' holds A.lo (for hi lanes)
            const float gs = (lane & 32) ? 0.f : g;   // vsrc' holds A.hi (for lo lanes)
            #pragma unroll
            for (int r = 0; r < 16; ++r) {
                float pd, ps;
                pl32(A[r], pd, ps);
                A[r] = fmaf(gd, pd, fmaf(gs, ps, C0 * A[r]));
            }
#else
            float p[16];
            #pragma unroll
            for (int r = 0; r < 16; ++r) p[r] = sx32(A[r], xaddr);
            #pragma unroll
            for (int r = 0; r < 16; ++r) A[r] = fmaf(C0, A[r], g * p[r]);
#endif
        }
        {   // w2 + pre C(1,2): xor8 (row_ror:8), ctrl lane b4
            const float g = (lane & 8) ? S2 : -S2;
            const bool cb = (lane & 16) != 0;
            const float al = cb ? g : C2, be = cb ? C2 : g;
            #pragma unroll
            for (int r = 0; r < 16; ++r) A[r] = fmaf(al, A[r], be * sx<8>(A[r]));
        }
        {   // w4 + pre C(3,4): xor2 (quad_perm), ctrl lane b2
            const float g = (lane & 2) ? S4 : -S4;
            const bool cb = (lane & 4) != 0;
            const float al = cb ? g : C4, be = cb ? C4 : g;
            #pragma unroll
            for (int r = 0; r < 16; ++r) A[r] = fmaf(al, A[r], be * sx<2>(A[r]));
        }
        {   // w6 + pre C(5,6): reg pairs (r, r+8), ctrl lane b0 (runtime)
            const bool cb = (lane & 1) != 0;
            const float a_lo = cb ? -S6 : C6, b_lo = cb ? C6 : -S6;
            const float a_hi = cb ?  S6 : C6, b_hi = cb ? C6 :  S6;
            #pragma unroll
            for (int r = 0; r < 8; ++r) {
                const float lo = A[r], hi = A[r + 8];
                A[r]     = fmaf(a_lo, lo, b_lo * hi);
                A[r + 8] = fmaf(a_hi, hi, b_hi * lo);
            }
        }
        {   // w8 + pre C(7,8): reg pairs (r, r+2), ctrl r bit2 (compile-time)
            #pragma unroll
            for (int r = 0; r < 16; ++r) {
                if (r & 2) continue;
                const float lo = A[r], hi = A[r + 2];
                if (r & 4) {
                    A[r]     = fmaf(-S8, lo, C8 * hi);
                    A[r + 2] = fmaf( S8, hi, C8 * lo);
                } else {
                    A[r]     = fmaf(C8, lo, -S8 * hi);
                    A[r + 2] = fmaf(C8, hi,  S8 * lo);
                }
            }
        }

        const float4 oa = *(const float4*)(ce + 12);
        const float4 ob = *(const float4*)(ce + 16);
        const float2 oc = *(const float2*)(ce + 20);
        const float C1=oa.x,S1=oa.y, C3=oa.z,S3=oa.w;
        const float C5=ob.x,S5=ob.y, C7=ob.z,S7=ob.w;
        const float C9=oc.x,S9=oc.y;

        {   // w1 + post C(0,1): partner lane^16, ctrl lane b5
            const float g = (lane & 16) ? S1 : -S1;
            const bool cb = fuse && ((lane & 32) != 0);
            const float al = cb ? -g : C1, be = cb ? C1 : g;
#if HAVE_PLSWAP
            const float bd = (lane & 16) ? be : 0.f;  // vdst' holds even-row vals (for odd rows)
            const float bs = (lane & 16) ? 0.f : be;  // vsrc' holds odd-row vals (for even rows)
            #pragma unroll
            for (int r = 0; r < 16; ++r) {
                float pd, ps;
                pl16(A[r], pd, ps);
                A[r] = fmaf(bd, pd, fmaf(bs, ps, al * A[r]));
            }
#else
            float p[16];
            #pragma unroll
            for (int r = 0; r < 16; ++r) p[r] = swz16(A[r]);
            #pragma unroll
            for (int r = 0; r < 16; ++r) A[r] = fmaf(al, A[r], be * p[r]);
#endif
        }
        {   // w3 + post C(2,3): xor4 (mirror o quad_perm), ctrl lane b3
            const float g = (lane & 4) ? S3 : -S3;
            const bool cb = fuse && ((lane & 8) != 0);
            const float al = cb ? -g : C3, be = cb ? C3 : g;
            #pragma unroll
            for (int r = 0; r < 16; ++r) A[r] = fmaf(al, A[r], be * sx<4>(A[r]));
        }
        {   // w5 + post C(4,5): xor1 (quad_perm), ctrl lane b1
            const float g = (lane & 1) ? S5 : -S5;
            const bool cb = fuse && ((lane & 2) != 0);
            const float al = cb ? -g : C5, be = cb ? C5 : g;
            #pragma unroll
            for (int r = 0; r < 16; ++r) A[r] = fmaf(al, A[r], be * sx<1>(A[r]));
        }
        {   // w7 + post C(6,7): reg pairs (r, r+4), ctrl r bit3 (+fuse)
            #pragma unroll
            for (int r = 0; r < 16; ++r) {
                if (r & 4) continue;
                const float lo = A[r], hi = A[r + 4];
                if (fuse && (r & 8)) {
                    A[r]     = fmaf( S7, lo, C7 * hi);
                    A[r + 4] = fmaf(-S7, hi, C7 * lo);
                } else {
                    A[r]     = fmaf(C7, lo, -S7 * hi);
                    A[r + 4] = fmaf(C7, hi,  S7 * lo);
                }
            }
        }
        {   // w9 + post C(8,9): reg pairs (r, r+1), ctrl r bit1 (+fuse)
            #pragma unroll
            for (int r = 0; r < 16; r += 2) {
                const float xv = A[r], yv = A[r + 1];
                if (fuse && (r & 2)) {
                    A[r]     = fmaf( S9, xv, C9 * yv);
                    A[r + 1] = fmaf(-S9, yv, C9 * xv);
                } else {
                    A[r]     = fmaf(C9, xv, -S9 * yv);
                    A[r + 1] = fmaf(C9, yv,  S9 * xv);
                }
            }
        }
    }

    // ---------- expvals <Z_w> ----------
    float tot = 0.f, q6 = 0.f, q7 = 0.f, q8 = 0.f, q9 = 0.f;
    #pragma unroll
    for (int r = 0; r < 16; ++r) {
        const float P = A[r] * A[r];
        tot += P;
        if (r & 8) q6 += P;
        if (r & 4) q7 += P;
        if (r & 2) q8 += P;
        if (r & 1) q9 += P;
    }
    float e[NQ];
    e[0] = (lane & 32) ? -tot : tot;
    e[1] = (lane & 16) ? -tot : tot;
    e[2] = (lane & 8)  ? -tot : tot;
    e[3] = (lane & 4)  ? -tot : tot;
    e[4] = (lane & 2)  ? -tot : tot;
    e[5] = (lane & 1)  ? -tot : tot;
    e[6] = fmaf(-2.f, q6, tot);
    e[7] = fmaf(-2.f, q7, tot);
    e[8] = fmaf(-2.f, q8, tot);
    e[9] = fmaf(-2.f, q9, tot);
    #pragma unroll
    for (int w = 0; w < NQ; ++w) e[w] = red64(e[w], xaddr);

    // ---------- output GEMM: lane = output column ----------
    if (b < B) {
        float o = b2[lane];
        #pragma unroll
        for (int w = 0; w < NQ; ++w) o = fmaf(e[w], W2[w * DOUT + lane], o);
        out[(size_t)b * DOUT + lane] = o;
    }
}

extern "C" void kernel_launch(void* const* d_in, const int* in_sizes, int n_in,
                              void* d_out, int out_size, void* d_ws, size_t ws_size,
                              hipStream_t stream) {
    const float* x  = (const float*)d_in[0];
    const float* W1 = (const float*)d_in[1];
    const float* b1 = (const float*)d_in[2];
    const float* qw = (const float*)d_in[3];
    const float* W2 = (const float*)d_in[4];
    const float* b2 = (const float*)d_in[5];
    float* out = (float*)d_out;

    const int B = in_sizes[0] / DIN;
    const int blocks = (B + 3) / 4;   // 4 samples (waves) per 256-thread block
    dqc_main<<<blocks, 256, 0, stream>>>(x, W1, b1, qw, W2, b2, out, B);
}

// Round 13
// 100.048 us; speedup vs baseline: 1.1876x; 1.1876x over previous
//
#include <hip/hip_runtime.h>

#define NQ 10
#define QD 6
#define DIN 512
#define DOUT 64

// All cross-lane via compiler intrinsics ONLY (R9/R10 lesson: inline-asm DPP
// is invisible to the hazard recognizer -> RA copies corrupt it).
template <int CTRL>
__device__ __forceinline__ float dppf(float v) {
    return __int_as_float(__builtin_amdgcn_mov_dpp(__float_as_int(v), CTRL, 0xF, 0xF, true));
}
template <int M>
__device__ __forceinline__ float sx(float v) {
    if constexpr (M == 1)       return dppf<0xB1>(v);   // quad_perm [1,0,3,2]
    else if constexpr (M == 2)  return dppf<0x4E>(v);   // quad_perm [2,3,0,1]
    else if constexpr (M == 4)  return dppf<0x1B>(dppf<0x141>(v));
    else                        return dppf<0x128>(v);  // row_ror:8
}
__device__ __forceinline__ float swz16(float v) {
    return __int_as_float(__builtin_amdgcn_ds_swizzle(__float_as_int(v), 0x401F));
}
__device__ __forceinline__ float sx32(float v, int xaddr) {
    return __int_as_float(__builtin_amdgcn_ds_bpermute(xaddr, __float_as_int(v)));
}
__device__ __forceinline__ float red64(float v, int xaddr) {
    v += dppf<0x128>(v); v += dppf<0x124>(v);
    v += dppf<0x122>(v); v += dppf<0x121>(v);
    v += swz16(v);
    v += sx32(v, xaddr);
    return v;
}
__device__ __forceinline__ float tanh_fast(float x) {
    const float e = __expf(2.0f * x);
    return 1.0f - __fdividef(2.0f, e + 1.0f);
}

// One wave64 = one sample. Amp idx = (lane<<4) | r; wires 0..5 = lane bits
// 5..0; w6..w9 = r bits 3..0.
// CNOT fusion (validated R3..R11):
//   pre-CNOT+RY : (al,be) = cbit ? ( g, C) : (C, g),  g = tbit ? S : -S
//   RY+post-CNOT: (al,be) = cbit ? (-g, C) : (C, g)
// Even phase: w0, w2+preC12, w4+preC34, w6+preC56, w8+preC78
// Odd  phase: w1+postC01, w3+postC23, w5+postC45, w7+postC67, w9+postC89
// E_0 folded into the initial state (bit relabel).
//
// NEW (R13): tangent form for compile-time-coefficient gates. A rotation
// pair-mix C*x -+ S*y == C*(x -+ t*y), t = S/C (|t|<=0.025 — safe). The
// uniform factor C per gate accumulates into F = prod(C) and is folded into
// the initial state. Gates w0,w7,w8,w9 (all layers) and w1,w3,w5 (last
// layer, no-fuse arm) lose one mul per element.
__global__ __launch_bounds__(256) void dqc_main(
    const float* __restrict__ x,
    const float* __restrict__ W1,
    const float* __restrict__ b1,
    const float* __restrict__ qw,
    const float* __restrict__ W2,
    const float* __restrict__ b2,
    float* __restrict__ out,
    const int B)
{
    // csl per layer (stride 24):
    // [C0,S0,C2,S2,C4,S4,C6,S6,C8,S8,pad2, C1,S1,C3,S3,C5,S5,C7,S7,C9,S9,pad2]
    // tsl per layer (stride 8): [T0,T7,T8,T9, T1,T3,T5, unused]
    __shared__ __align__(16) float csl[QD * 24];
    __shared__ __align__(16) float tsl[QD * 8];

    const int tid = threadIdx.x;
    if (tid < QD * NQ) {
        const int layer = tid / NQ, wire = tid - layer * NQ;
        const float h = qw[tid] * 0.5f;
        const float s = __sinf(h), c = __cosf(h);
        const int pos = layer * 24 + (wire & 1) * 12 + (wire >> 1) * 2;
        csl[pos] = c; csl[pos + 1] = s;
        int slot = -1;
        if (wire == 0) slot = 0; else if (wire == 7) slot = 1;
        else if (wire == 8) slot = 2; else if (wire == 9) slot = 3;
        else if (wire == 1) slot = 4; else if (wire == 3) slot = 5;
        else if (wire == 5) slot = 6;
        if (slot >= 0) tsl[layer * 8 + slot] = __fdividef(s, c);
    }

    const int lane = tid & 63;
    const int b = blockIdx.x * 4 + (tid >> 6);
    const int bb = (b < B) ? b : (B - 1);
    const int xaddr = ((tid ^ 32) & 63) << 2;   // bpermute addr: lane^32

    // ---------- front-end: dot = x[b,:] @ W1 ----------
    float xr[8];
    {
        const float4* xp = (const float4*)(x + (size_t)bb * DIN + lane * 8);
        const float4 v0 = xp[0], v1 = xp[1];
        xr[0]=v0.x; xr[1]=v0.y; xr[2]=v0.z; xr[3]=v0.w;
        xr[4]=v1.x; xr[5]=v1.y; xr[6]=v1.z; xr[7]=v1.w;
    }
    float dot[NQ];
    #pragma unroll
    for (int w = 0; w < NQ; ++w) dot[w] = 0.f;
    {
        const float4* wp = (const float4*)(W1 + (size_t)lane * 8 * NQ);
        #pragma unroll
        for (int j = 0; j < 4; ++j) {
            const float4 f0 = wp[5*j], f1 = wp[5*j+1], f2 = wp[5*j+2],
                         f3 = wp[5*j+3], f4 = wp[5*j+4];
            const float xa = xr[2*j], xb = xr[2*j+1];
            dot[0]=fmaf(xa,f0.x,dot[0]); dot[1]=fmaf(xa,f0.y,dot[1]);
            dot[2]=fmaf(xa,f0.z,dot[2]); dot[3]=fmaf(xa,f0.w,dot[3]);
            dot[4]=fmaf(xa,f1.x,dot[4]); dot[5]=fmaf(xa,f1.y,dot[5]);
            dot[6]=fmaf(xa,f1.z,dot[6]); dot[7]=fmaf(xa,f1.w,dot[7]);
            dot[8]=fmaf(xa,f2.x,dot[8]); dot[9]=fmaf(xa,f2.y,dot[9]);
            dot[0]=fmaf(xb,f2.z,dot[0]); dot[1]=fmaf(xb,f2.w,dot[1]);
            dot[2]=fmaf(xb,f3.x,dot[2]); dot[3]=fmaf(xb,f3.y,dot[3]);
            dot[4]=fmaf(xb,f3.z,dot[4]); dot[5]=fmaf(xb,f3.w,dot[5]);
            dot[6]=fmaf(xb,f4.x,dot[6]); dot[7]=fmaf(xb,f4.y,dot[7]);
            dot[8]=fmaf(xb,f4.z,dot[8]); dot[9]=fmaf(xb,f4.w,dot[9]);
        }
    }
    #pragma unroll
    for (int w = 0; w < NQ; ++w) dot[w] = red64(dot[w], xaddr);

    // u0 = cos(th2+pi/4), u1 = sin(th2+pi/4), th2 = tanh(dot+b1)*pi/4
    float u0[NQ], u1[NQ];
    #pragma unroll
    for (int w = 0; w < NQ; ++w) {
        const float phi = fmaf(tanh_fast(dot[w] + b1[w]),
                               0.78539816339744830962f, 0.78539816339744830962f);
        u0[w] = __cosf(phi);
        u1[w] = __sinf(phi);
    }

    __syncthreads();  // csl/tsl ready (no early return above)

    // ---------- extracted factor F = prod of C over t-form gates ----------
    float F = 1.f;
    #pragma unroll
    for (int k = 0; k < QD; ++k) {
        const float* ce = csl + k * 24;
        F *= ce[0] * ce[18];    // C0 * C7
        F *= ce[8] * ce[20];    // C8 * C9
    }
    {   const float* c5 = csl + 5 * 24;
        F *= c5[12] * c5[14];   // C1 * C3 (last layer no-fuse t-form)
        F *= c5[16];            // C5
    }

    // ---------- initial product state, E_0 relabel + F folded ----------
    // w0@b5, w1@b4^b5, w2@b3, w3@b2^b3, w4@b1, w5@b0^b1 (lane);
    // w6@r3, w7@r2^r3, w8@r1, w9@r0^r1 (register) — prefix-doubling build.
    float A[16];
    {
        float lf = ((lane & 32) ? u1[0] : u0[0]);
        lf *= ((((lane >> 4) ^ (lane >> 5)) & 1) ? u1[1] : u0[1]);
        lf *= ((lane & 8) ? u1[2] : u0[2]);
        lf *= ((((lane >> 2) ^ (lane >> 3)) & 1) ? u1[3] : u0[3]);
        lf *= ((lane & 2) ? u1[4] : u0[4]);
        lf *= (((lane ^ (lane >> 1)) & 1) ? u1[5] : u0[5]);
        lf *= F;
        float d1[2] = { lf * u0[6], lf * u1[6] };
        float d2[4], d3[8];
        #pragma unroll
        for (int i = 0; i < 4; ++i) {
            const int r3 = i >> 1, r2 = i & 1;
            d2[i] = d1[r3] * (((r2 ^ r3) & 1) ? u1[7] : u0[7]);
        }
        #pragma unroll
        for (int i = 0; i < 8; ++i)
            d3[i] = d2[i >> 1] * ((i & 1) ? u1[8] : u0[8]);
        #pragma unroll
        for (int i = 0; i < 8; ++i) {
            const int r1 = i & 1;
            A[2*i]   = d3[i] * (r1 ? u1[9] : u0[9]);   // r0=0: r0^r1 = r1
            A[2*i+1] = d3[i] * (r1 ? u0[9] : u1[9]);   // r0=1: r0^r1 = !r1
        }
    }

    // ---------- 6 fused layers ----------
    #pragma unroll 1
    for (int k = 0; k < QD; ++k) {
        const float* ce = csl + k * 24;
        const float4 ea = *(const float4*)(ce);
        const float4 eb = *(const float4*)(ce + 4);
        const float4 tv = *(const float4*)(tsl + k * 8);
        const float C2=ea.z,S2=ea.w, C4=eb.x,S4=eb.y, C6=eb.z,S6=eb.w;
        const float T0=tv.x, T7=tv.y, T8=tv.z, T9=tv.w;

        // ==== even phase ====
        {   // w0 (t-form): partner lane^32
            const float t0 = (lane & 32) ? T0 : -T0;
            float p[16];
            #pragma unroll
            for (int r = 0; r < 16; ++r) p[r] = sx32(A[r], xaddr);
            #pragma unroll
            for (int r = 0; r < 16; ++r) A[r] = fmaf(t0, p[r], A[r]);
        }
        {   // w2 + pre C(1,2): xor8 (row_ror:8), ctrl lane b4
            const float g = (lane & 8) ? S2 : -S2;
            const bool cb = (lane & 16) != 0;
            const float al = cb ? g : C2, be = cb ? C2 : g;
            #pragma unroll
            for (int r = 0; r < 16; ++r) A[r] = fmaf(al, A[r], be * sx<8>(A[r]));
        }
        {   // w4 + pre C(3,4): xor2 (quad_perm), ctrl lane b2
            const float g = (lane & 2) ? S4 : -S4;
            const bool cb = (lane & 4) != 0;
            const float al = cb ? g : C4, be = cb ? C4 : g;
            #pragma unroll
            for (int r = 0; r < 16; ++r) A[r] = fmaf(al, A[r], be * sx<2>(A[r]));
        }
        {   // w6 + pre C(5,6): reg pairs (r, r+8), ctrl lane b0 (runtime)
            const bool cb = (lane & 1) != 0;
            const float a_lo = cb ? -S6 : C6, b_lo = cb ? C6 : -S6;
            const float a_hi = cb ?  S6 : C6, b_hi = cb ? C6 :  S6;
            #pragma unroll
            for (int r = 0; r < 8; ++r) {
                const float lo = A[r], hi = A[r + 8];
                A[r]     = fmaf(a_lo, lo, b_lo * hi);
                A[r + 8] = fmaf(a_hi, hi, b_hi * lo);
            }
        }
        {   // w8 + pre C(7,8) (t-form): reg pairs (r, r+2), ctrl r bit2
            #pragma unroll
            for (int r = 0; r < 16; ++r) {
                if (r & 2) continue;
                const float lo = A[r], hi = A[r + 2];
                if (r & 4) {
                    A[r]     = fmaf(-T8, lo, hi);
                    A[r + 2] = fmaf( T8, hi, lo);
                } else {
                    A[r]     = fmaf(-T8, hi, lo);
                    A[r + 2] = fmaf( T8, lo, hi);
                }
            }
        }

        // ==== odd phase (fuse arm compile-time per branch) ====
        if (k != QD - 1) {
            const float4 oa = *(const float4*)(ce + 12);
            const float2 ob = *(const float2*)(ce + 16);
            const float C1=oa.x,S1=oa.y, C3=oa.z,S3=oa.w, C5=ob.x,S5=ob.y;

            {   // w1 + post C(0,1): xor16 (ds_swizzle), ctrl lane b5
                const float g = (lane & 16) ? S1 : -S1;
                const bool cb = (lane & 32) != 0;
                const float al = cb ? -g : C1, be = cb ? C1 : g;
                float p[16];
                #pragma unroll
                for (int r = 0; r < 16; ++r) p[r] = swz16(A[r]);
                #pragma unroll
                for (int r = 0; r < 16; ++r) A[r] = fmaf(al, A[r], be * p[r]);
            }
            {   // w3 + post C(2,3): xor4, ctrl lane b3
                const float g = (lane & 4) ? S3 : -S3;
                const bool cb = (lane & 8) != 0;
                const float al = cb ? -g : C3, be = cb ? C3 : g;
                #pragma unroll
                for (int r = 0; r < 16; ++r) A[r] = fmaf(al, A[r], be * sx<4>(A[r]));
            }
            {   // w5 + post C(4,5): xor1, ctrl lane b1
                const float g = (lane & 1) ? S5 : -S5;
                const bool cb = (lane & 2) != 0;
                const float al = cb ? -g : C5, be = cb ? C5 : g;
                #pragma unroll
                for (int r = 0; r < 16; ++r) A[r] = fmaf(al, A[r], be * sx<1>(A[r]));
            }
            {   // w7 + post C(6,7) (t-form, fuse): pairs (r, r+4), ctrl r bit3
                #pragma unroll
                for (int r = 0; r < 16; ++r) {
                    if (r & 4) continue;
                    const float lo = A[r], hi = A[r + 4];
                    if (r & 8) {
                        A[r]     = fmaf( T7, lo, hi);
                        A[r + 4] = fmaf(-T7, hi, lo);
                    } else {
                        A[r]     = fmaf(-T7, hi, lo);
                        A[r + 4] = fmaf( T7, lo, hi);
                    }
                }
            }
            {   // w9 + post C(8,9) (t-form, fuse): pairs (r, r+1), ctrl r bit1
                #pragma unroll
                for (int r = 0; r < 16; r += 2) {
                    const float xv = A[r], yv = A[r + 1];
                    if (r & 2) {
                        A[r]     = fmaf( T9, xv, yv);
                        A[r + 1] = fmaf(-T9, yv, xv);
                    } else {
                        A[r]     = fmaf(-T9, yv, xv);
                        A[r + 1] = fmaf( T9, xv, yv);
                    }
                }
            }
        } else {
            // last layer: no post-CNOT anywhere -> all plain RY, all t-form
            const float4 tv2 = *(const float4*)(tsl + k * 8 + 4);
            const float T1 = tv2.x, T3 = tv2.y, T5 = tv2.z;

            {   // w1: xor16
                const float t1 = (lane & 16) ? T1 : -T1;
                float p[16];
                #pragma unroll
                for (int r = 0; r < 16; ++r) p[r] = swz16(A[r]);
                #pragma unroll
                for (int r = 0; r < 16; ++r) A[r] = fmaf(t1, p[r], A[r]);
            }
            {   // w3: xor4
                const float t3 = (lane & 4) ? T3 : -T3;
                #pragma unroll
                for (int r = 0; r < 16; ++r) A[r] = fmaf(t3, sx<4>(A[r]), A[r]);
            }
            {   // w5: xor1
                const float t5 = (lane & 1) ? T5 : -T5;
                #pragma unroll
                for (int r = 0; r < 16; ++r) A[r] = fmaf(t5, sx<1>(A[r]), A[r]);
            }
            {   // w7 (t-form, no fuse)
                #pragma unroll
                for (int r = 0; r < 16; ++r) {
                    if (r & 4) continue;
                    const float lo = A[r], hi = A[r + 4];
                    A[r]     = fmaf(-T7, hi, lo);
                    A[r + 4] = fmaf( T7, lo, hi);
                }
            }
            {   // w9 (t-form, no fuse)
                #pragma unroll
                for (int r = 0; r < 16; r += 2) {
                    const float xv = A[r], yv = A[r + 1];
                    A[r]     = fmaf(-T9, yv, xv);
                    A[r + 1] = fmaf( T9, xv, yv);
                }
            }
        }
    }

    // ---------- expvals <Z_w> ----------
    float tot = 0.f, q6 = 0.f, q7 = 0.f, q8 = 0.f, q9 = 0.f;
    #pragma unroll
    for (int r = 0; r < 16; ++r) {
        const float P = A[r] * A[r];
        tot += P;
        if (r & 8) q6 += P;
        if (r & 4) q7 += P;
        if (r & 2) q8 += P;
        if (r & 1) q9 += P;
    }
    float e[NQ];
    e[0] = (lane & 32) ? -tot : tot;
    e[1] = (lane & 16) ? -tot : tot;
    e[2] = (lane & 8)  ? -tot : tot;
    e[3] = (lane & 4)  ? -tot : tot;
    e[4] = (lane & 2)  ? -tot : tot;
    e[5] = (lane & 1)  ? -tot : tot;
    e[6] = fmaf(-2.f, q6, tot);
    e[7] = fmaf(-2.f, q7, tot);
    e[8] = fmaf(-2.f, q8, tot);
    e[9] = fmaf(-2.f, q9, tot);
    #pragma unroll
    for (int w = 0; w < NQ; ++w) e[w] = red64(e[w], xaddr);

    // ---------- output GEMM: lane = output column ----------
    if (b < B) {
        float o = b2[lane];
        #pragma unroll
        for (int w = 0; w < NQ; ++w) o = fmaf(e[w], W2[w * DOUT + lane], o);
        out[(size_t)b * DOUT + lane] = o;
    }
}

extern "C" void kernel_launch(void* const* d_in, const int* in_sizes, int n_in,
                              void* d_out, int out_size, void* d_ws, size_t ws_size,
                              hipStream_t stream) {
    const float* x  = (const float*)d_in[0];
    const float* W1 = (const float*)d_in[1];
    const float* b1 = (const float*)d_in[2];
    const float* qw = (const float*)d_in[3];
    const float* W2 = (const float*)d_in[4];
    const float* b2 = (const float*)d_in[5];
    float* out = (float*)d_out;

    const int B = in_sizes[0] / DIN;
    const int blocks = (B + 3) / 4;   // 4 samples (waves) per 256-thread block
    dqc_main<<<blocks, 256, 0, stream>>>(x, W1, b1, qw, W2, b2, out, B);
}